// Round 4
// baseline (278.949 us; speedup 1.0000x reference)
//
#include <hip/hip_runtime.h>

#define B_ 4
#define S_ 4096
#define E_ 1024
#define H_ 128
#define M_ (B_*S_)   // 16384

typedef __attribute__((ext_vector_type(8))) short bf16x8;
typedef __attribute__((ext_vector_type(4))) float f32x4;
typedef __attribute__((ext_vector_type(2))) unsigned int uint2v;

__device__ inline ushort f2bf(float f) {
  union { float f; unsigned u; } v; v.f = f;
  unsigned r = v.u + 0x7fffu + ((v.u >> 16) & 1u);   // RNE
  return (ushort)(r >> 16);
}

// ---- gfx950 cross-lane primitives (register-file, ~2cyc vs ~120cyc ds_bpermute) ----
__device__ inline void pl16sw(unsigned &x, unsigned &y) {
#if __has_builtin(__builtin_amdgcn_permlane16_swap)
  uint2v r = __builtin_amdgcn_permlane16_swap(x, y, false, false);
  x = r.x; y = r.y;
#else
  asm("v_permlane16_swap_b32 %0, %1" : "+v"(x), "+v"(y));
#endif
}
__device__ inline void pl32sw(unsigned &x, unsigned &y) {
#if __has_builtin(__builtin_amdgcn_permlane32_swap)
  uint2v r = __builtin_amdgcn_permlane32_swap(x, y, false, false);
  x = r.x; y = r.y;
#else
  asm("v_permlane32_swap_b32 %0, %1" : "+v"(x), "+v"(y));
#endif
}
// reduce over the 4 quads (lanes {col, col+16, col+32, col+48}); result broadcast to all
__device__ inline float red4max(float v) {
  union { float f; unsigned u; } a, b;
  a.f = v; b.f = v; pl16sw(a.u, b.u);
  float m1 = fmaxf(a.f, b.f);
  a.f = m1; b.f = m1; pl32sw(a.u, b.u);
  return fmaxf(a.f, b.f);
}
__device__ inline float red4sum(float v) {
  union { float f; unsigned u; } a, b;
  a.f = v; b.f = v; pl16sw(a.u, b.u);
  float s1 = a.f + b.f;
  a.f = s1; b.f = s1; pl32sw(a.u, b.u);
  return a.f + b.f;
}
__device__ inline unsigned cvt_pk_bf16(float lo, float hi) {
  unsigned w;
  asm("v_cvt_pk_bf16_f32 %0, %1, %2" : "=v"(w) : "v"(lo), "v"(hi));
  return w;
}

#define GLLDS16(g, l) __builtin_amdgcn_global_load_lds( \
    (const __attribute__((address_space(1))) void*)(g), \
    (__attribute__((address_space(3))) void*)(l), 16, 0, 0)

// ---------- kernel 1: W [1024][128] f32 (x3) -> Wt [3][128][1024] bf16 ----------
__global__ __launch_bounds__(256) void wt_kernel(const float* __restrict__ Wq,
    const float* __restrict__ Wk, const float* __restrict__ Wv,
    ushort* __restrict__ Wt) {
  int bid = blockIdx.x;               // 384 = 3 mats * 4 h-tiles * 32 e-tiles
  int mat = bid >> 7;
  int rem = bid & 127;
  int ht = rem >> 5, et = rem & 31;
  const float* W = mat == 0 ? Wq : (mat == 1 ? Wk : Wv);
  int e0 = et * 32, h0 = ht * 32;
  __shared__ float tl[32][33];
  int t = threadIdx.x;
  int r = t >> 3, c = (t & 7) << 2;
  const float4 f = *(const float4*)(W + (size_t)(e0 + r) * H_ + h0 + c);
  tl[r][c] = f.x; tl[r][c+1] = f.y; tl[r][c+2] = f.z; tl[r][c+3] = f.w;
  __syncthreads();
  ushort4 o;
  o.x = f2bf(tl[c+0][r]); o.y = f2bf(tl[c+1][r]);
  o.z = f2bf(tl[c+2][r]); o.w = f2bf(tl[c+3][r]);
  *(ushort4*)(Wt + ((size_t)mat*H_ + h0 + r) * E_ + e0 + c) = o;
}

// ---------- kernel 2: x f32 -> bf16 (memory-bound) ----------
__global__ __launch_bounds__(256) void xb_kernel(const float* __restrict__ x,
                                                 ushort* __restrict__ xb) {
  size_t i = ((size_t)blockIdx.x * 256 + threadIdx.x) * 8;
  float4 f0 = *(const float4*)(x + i);
  float4 f1 = *(const float4*)(x + i + 4);
  alignas(16) ushort us[8];
  us[0]=f2bf(f0.x); us[1]=f2bf(f0.y); us[2]=f2bf(f0.z); us[3]=f2bf(f0.w);
  us[4]=f2bf(f1.x); us[5]=f2bf(f1.y); us[6]=f2bf(f1.z); us[7]=f2bf(f1.w);
  *(uint4*)(xb + i) = *(uint4*)&us[0];
}

// ---------- kernel 3: QKV GEMM, m97-style: 128x128 tile, BK=64, global_load_lds ----------
__global__ __launch_bounds__(256, 2) void qkv_gemm(const ushort* __restrict__ xb,
    const ushort* __restrict__ Wt, ushort* __restrict__ qo,
    ushort* __restrict__ ko, ushort* __restrict__ vTo) {
  const int m0 = blockIdx.x * 128;
  const int mat = blockIdx.y;
  const ushort* Bsrc = Wt + (size_t)mat * H_ * E_;
  __shared__ ushort As[2][128 * 64];
  __shared__ ushort Bs[2][128 * 64];
  const int tid = threadIdx.x;
  const int wave = tid >> 6, lane = tid & 63;
  const int col = lane & 15, quad = lane >> 4;
  const int wr = wave >> 1, wc = wave & 1;

  f32x4 acc[4][4];
  #pragma unroll
  for (int i = 0; i < 4; i++)
    #pragma unroll
    for (int j = 0; j < 4; j++) acc[i][j] = (f32x4){0.f,0.f,0.f,0.f};

  const int srow = lane >> 3;
  const int sunit = (lane & 7) ^ srow;
  const int gcol = sunit * 8;

  #define STAGE_QKV(it, bufi) do { \
    _Pragma("unroll") \
    for (int j = 0; j < 4; j++) { \
      int rbase = wave*8 + j*32; \
      GLLDS16(xb + (size_t)(m0 + rbase + srow) * E_ + (it)*64 + gcol, \
              &As[bufi][rbase * 64]); \
      GLLDS16(Bsrc + (size_t)(rbase + srow) * E_ + (it)*64 + gcol, \
              &Bs[bufi][rbase * 64]); \
    } \
  } while (0)

  STAGE_QKV(0, 0);
  __syncthreads();

  for (int it = 0; it < 16; it++) {
    if (it < 15) STAGE_QKV(it + 1, (it + 1) & 1);
    const ushort* a = &As[it & 1][0];
    const ushort* bb = &Bs[it & 1][0];
    #pragma unroll
    for (int kc = 0; kc < 2; kc++) {
      bf16x8 af[4], bf[4];
      #pragma unroll
      for (int mi = 0; mi < 4; mi++) {
        int rr = wr*64 + mi*16 + col;
        af[mi] = *(const bf16x8*)(a + rr*64 + (((kc*4 + quad) ^ (col & 7)) * 8));
      }
      #pragma unroll
      for (int ni = 0; ni < 4; ni++) {
        int rr = wc*64 + ni*16 + col;
        bf[ni] = *(const bf16x8*)(bb + rr*64 + (((kc*4 + quad) ^ (col & 7)) * 8));
      }
      #pragma unroll
      for (int mi = 0; mi < 4; mi++)
        #pragma unroll
        for (int ni = 0; ni < 4; ni++)
          acc[mi][ni] = __builtin_amdgcn_mfma_f32_16x16x32_bf16(af[mi], bf[ni], acc[mi][ni], 0, 0, 0);
    }
    __syncthreads();
  }

  if (mat == 2) {
    int bb = m0 >> 12;
    int sbase = (m0 & 4095) + wr * 64;
    #pragma unroll
    for (int ni = 0; ni < 4; ni++) {
      int n = wc*64 + ni*16 + col;
      #pragma unroll
      for (int mi = 0; mi < 4; mi++) {
        int s = sbase + mi*16 + quad*4;
        ushort4 o;
        o.x = f2bf(acc[mi][ni][0]); o.y = f2bf(acc[mi][ni][1]);
        o.z = f2bf(acc[mi][ni][2]); o.w = f2bf(acc[mi][ni][3]);
        *(ushort4*)(vTo + ((size_t)(bb * H_ + n)) * S_ + s) = o;
      }
    }
  } else {
    ushort* dst = (mat == 0 ? qo : ko);
    #pragma unroll
    for (int ni = 0; ni < 4; ni++) {
      int n = wc*64 + ni*16 + col;
      #pragma unroll
      for (int mi = 0; mi < 4; mi++) {
        int row = m0 + wr*64 + mi*16 + quad*4;
        #pragma unroll
        for (int r = 0; r < 4; r++)
          dst[(size_t)(row + r) * H_ + n] = f2bf(acc[mi][ni][r]);
      }
    }
  }
}

// ---------- kernel 4: causal flash, split-K, ONE 64-row tile per WG, KVBLK=64 ----------
// grid (c=8, t=64 reversed, b=4): 1152 active blocks.
// K staged via global_load_lds: LDS dest linear (tid*16B), swizzle on GLOBAL source (m173).
// ROUND-3 LESSON (rule #20): never take a pointer into a local array -- `p + hh*8`
// demoted p[16]/s[16] to scratch (VGPR 112->76, dur 84.8->150us). All accesses below
// are compile-time-static.
#define CHUNK_ 512
#define KB_ 64
__global__ __launch_bounds__(256, 2) void flash_kernel(const ushort* __restrict__ q,
    const ushort* __restrict__ k, const ushort* __restrict__ vT,
    float* __restrict__ Opart, float* __restrict__ ml) {
  const float SL2E = 0.08838834764831845f * 1.44269504088896340736f;
  int c = blockIdx.x;
  int t = 63 - (int)blockIdx.y;               // heavy tiles first
  int b = blockIdx.z;
  if (t < 8 * c) return;
  int a = t >> 3, rr = t & 7;
  int slot = b * 288 + (a + 1) * (4 * a + rr) + c;

  int tid = threadIdx.x;
  int wave = tid >> 6, lane = tid & 63;
  int col = lane & 15, quad = lane >> 4;
  int q0 = t * 64 + wave * 16;
  const ushort* qb = q + (size_t)b * S_ * H_;
  const ushort* kbp = k + (size_t)b * S_ * H_;
  const ushort* vb = vT + (size_t)b * H_ * S_;

  __shared__ ushort kl[2][64 * 128];          // 64-key K block double-buffer (32 KB)

  bf16x8 qf[4];
  {
    const ushort* qp = qb + (size_t)(q0 + col) * H_ + quad * 8;
    #pragma unroll
    for (int kc = 0; kc < 4; kc++) qf[kc] = *(const bf16x8*)(qp + kc * 32);
  }

  f32x4 O[8];
  #pragma unroll
  for (int d = 0; d < 8; d++) O[d] = (f32x4){0.f,0.f,0.f,0.f};
  float m = -1e30f, l = 0.f;

  const int c0 = c * CHUNK_;
  const int kend = min(c0 + CHUNK_, t * 64 + 64);
  const int nblk = (kend - c0) >> 6;          // always multiple of 64
  const int qlim = q0 + 15;

  // K staging: thread tid -> row (tid>>4)+16j, unit tid&15; LDS linear in tid*16B.
  const int sr = tid >> 4;
  const int gu = ((tid & 15) ^ (sr & 15)) * 8;
  const int lbase = wave * 512;
  const size_t lbuf = 64 * 128;

  const ushort* vbase = vb + (size_t)col * S_ + c0 + quad * 8;

  #define STAGE_K(kb, bufi) do { \
    _Pragma("unroll") \
    for (int j = 0; j < 4; j++) { \
      GLLDS16(kbp + (size_t)((kb) + sr + j * 16) * H_ + gu, \
              &kl[0][(bufi) * lbuf + lbase + j * 2048]); \
    } \
  } while (0)

  STAGE_K(c0, 0);
  __syncthreads();

  for (int ib = 0; ib < nblk; ib++) {
    const int kb0 = c0 + ib * KB_;
    if (ib + 1 < nblk) STAGE_K(kb0 + KB_, (ib + 1) & 1);   // T14: async, drained at barrier
    if (kb0 <= qlim) {                        // wave-uniform
      const ushort* kcur = &kl[ib & 1][0];
      // --- QK^T: 4 independent sub-block chains ---
      f32x4 sv[4];
      #pragma unroll
      for (int sb = 0; sb < 4; sb++) sv[sb] = (f32x4){0.f,0.f,0.f,0.f};
      __builtin_amdgcn_s_setprio(1);
      #pragma unroll
      for (int sb = 0; sb < 4; sb++) {
        bf16x8 kf[4];
        #pragma unroll
        for (int kc = 0; kc < 4; kc++)
          kf[kc] = *(const bf16x8*)(kcur + (sb * 16 + col) * 128 + (((quad + kc * 4) ^ col) * 8));
        #pragma unroll
        for (int kc = 0; kc < 4; kc++)
          sv[sb] = __builtin_amdgcn_mfma_f32_16x16x32_bf16(kf[kc], qf[kc], sv[sb], 0, 0, 0);
      }
      __builtin_amdgcn_s_setprio(0);
      // V fragments group 0 (d=0..3): issue before softmax
      bf16x8 vf0[4], vf1[4];
      #pragma unroll
      for (int j = 0; j < 4; j++)
        vf0[j] = *(const bf16x8*)(vbase + ib * KB_ + (size_t)(j * 16) * S_);
      // --- softmax over 16 scores; s[sb*4+r] = key kb0+sb*16+quad*4+r, row q0+col ---
      float s[16];
      #pragma unroll
      for (int sb = 0; sb < 4; sb++)
        #pragma unroll
        for (int r = 0; r < 4; r++) s[sb * 4 + r] = sv[sb][r];
      if (kb0 + 63 > q0) {
        #pragma unroll
        for (int sb = 0; sb < 4; sb++)
          #pragma unroll
          for (int r = 0; r < 4; r++)
            if (kb0 + sb * 16 + quad * 4 + r > q0 + col) s[sb * 4 + r] = -1e30f;
      }
      float cm = s[0];
      #pragma unroll
      for (int j = 1; j < 16; j++) cm = fmaxf(cm, s[j]);
      cm = red4max(cm);
      if (!__all(cm <= m)) {                  // T13 exact skip (alpha==1 bit-identical)
        float mn = fmaxf(m, cm);
        float alpha = exp2f((m - mn) * SL2E);
        l *= alpha;
        #pragma unroll
        for (int d = 0; d < 8; d++) O[d] *= alpha;
        m = mn;
      }
      // V group 1 (d=4..7): issue mid-softmax
      #pragma unroll
      for (int j = 0; j < 4; j++)
        vf1[j] = *(const bf16x8*)(vbase + ib * KB_ + (size_t)((4 + j) * 16) * S_);
      float p[16], rs = 0.f;
      #pragma unroll
      for (int j = 0; j < 16; j++) { p[j] = exp2f((s[j] - m) * SL2E); rs += p[j]; }
      l += red4sum(rs);
      // --- P -> two bf16x8 fragments, ALL-STATIC indexing (no pointer into p!) ---
      unsigned wa0 = cvt_pk_bf16(p[0],  p[1]);
      unsigned wa1 = cvt_pk_bf16(p[2],  p[3]);
      unsigned wa2 = cvt_pk_bf16(p[4],  p[5]);
      unsigned wa3 = cvt_pk_bf16(p[6],  p[7]);
      pl32sw(wa0, wa2); pl32sw(wa1, wa3);
      pl16sw(wa0, wa2); pl16sw(wa1, wa3);
      unsigned wb0 = cvt_pk_bf16(p[8],  p[9]);
      unsigned wb1 = cvt_pk_bf16(p[10], p[11]);
      unsigned wb2 = cvt_pk_bf16(p[12], p[13]);
      unsigned wb3 = cvt_pk_bf16(p[14], p[15]);
      pl32sw(wb0, wb2); pl32sw(wb1, wb3);
      pl16sw(wb0, wb2); pl16sw(wb1, wb3);
      union { uint4 u4; bf16x8 v; } pu0, pu1;
      pu0.u4 = make_uint4(wa0, wa1, wa2, wa3);
      pu1.u4 = make_uint4(wb0, wb1, wb2, wb3);
      // --- PV: rolling V groups; second-half groups loaded just-in-time ---
      bf16x8 vf2[4];
      #pragma unroll
      for (int j = 0; j < 4; j++)
        vf2[j] = *(const bf16x8*)(vbase + ib * KB_ + 32 + (size_t)(j * 16) * S_);
      __builtin_amdgcn_s_setprio(1);
      #pragma unroll
      for (int j = 0; j < 4; j++)
        O[j] = __builtin_amdgcn_mfma_f32_16x16x32_bf16(vf0[j], pu0.v, O[j], 0, 0, 0);
      __builtin_amdgcn_s_setprio(0);
      bf16x8 vf3[4];
      #pragma unroll
      for (int j = 0; j < 4; j++)
        vf3[j] = *(const bf16x8*)(vbase + ib * KB_ + 32 + (size_t)((4 + j) * 16) * S_);
      __builtin_amdgcn_s_setprio(1);
      #pragma unroll
      for (int j = 0; j < 4; j++)
        O[4 + j] = __builtin_amdgcn_mfma_f32_16x16x32_bf16(vf1[j], pu0.v, O[4 + j], 0, 0, 0);
      #pragma unroll
      for (int j = 0; j < 4; j++)
        O[j] = __builtin_amdgcn_mfma_f32_16x16x32_bf16(vf2[j], pu1.v, O[j], 0, 0, 0);
      #pragma unroll
      for (int j = 0; j < 4; j++)
        O[4 + j] = __builtin_amdgcn_mfma_f32_16x16x32_bf16(vf3[j], pu1.v, O[4 + j], 0, 0, 0);
      __builtin_amdgcn_s_setprio(0);
    }
    __syncthreads();                          // drains staging vmcnt for next buffer
  }

  float* Op = Opart + (size_t)slot * (64 * 128) + (size_t)(wave * 16 + col) * 128 + quad * 4;
  #pragma unroll
  for (int d = 0; d < 8; d++) *(f32x4*)(Op + d * 16) = O[d];
  if (quad == 0)
    *(float2*)(ml + (size_t)slot * 128 + (size_t)(wave * 16 + col) * 2) = make_float2(m, l);
}

// ---------- kernel 5: combine split-K partials ----------
__global__ __launch_bounds__(256) void combine_kernel(const float* __restrict__ Opart,
    const float* __restrict__ ml, float* __restrict__ out) {
  const float SL2E = 0.08838834764831845f * 1.44269504088896340736f;
  int tile = blockIdx.x, b = blockIdx.y;
  int a = tile >> 3, rr = tile & 7;
  int nc = a + 1;
  int base = b * 288 + (a + 1) * (4 * a + rr);
  int tid = threadIdx.x;
  int row = tid >> 2;
  int cs = (tid & 3) * 4;
  float m_c[8], l_c[8];
  float mstar = -1e30f;
  for (int ci = 0; ci < nc; ci++) {
    m_c[ci] = ml[(size_t)(base + ci) * 128 + row * 2];
    l_c[ci] = ml[(size_t)(base + ci) * 128 + row * 2 + 1];
    mstar = fmaxf(mstar, m_c[ci]);
  }
  float denom = 0.f;
  float w_c[8];
  for (int ci = 0; ci < nc; ci++) {
    w_c[ci] = exp2f((m_c[ci] - mstar) * SL2E);
    denom += w_c[ci] * l_c[ci];
  }
  float inv = 1.f / denom;
  f32x4 acc[8];
  #pragma unroll
  for (int i = 0; i < 8; i++) acc[i] = (f32x4){0.f,0.f,0.f,0.f};
  for (int ci = 0; ci < nc; ci++) {
    const float* Op = Opart + (size_t)(base + ci) * (64 * 128) + row * 128;
    float w = w_c[ci];
    #pragma unroll
    for (int i = 0; i < 8; i++) {
      f32x4 v = *(const f32x4*)(Op + cs + i * 16);
      acc[i] += w * v;
    }
  }
  float* o = out + ((size_t)(b * S_) + tile * 64 + row) * H_;
  #pragma unroll
  for (int i = 0; i < 8; i++) {
    f32x4 v = acc[i] * inv;
    *(f32x4*)(o + cs + i * 16) = v;
  }
}

extern "C" void kernel_launch(void* const* d_in, const int* in_sizes, int n_in,
                              void* d_out, int out_size, void* d_ws, size_t ws_size,
                              hipStream_t stream) {
  (void)in_sizes; (void)n_in; (void)out_size; (void)ws_size;
  const float* x  = (const float*)d_in[0];
  const float* Wq = (const float*)d_in[1];
  const float* Wk = (const float*)d_in[2];
  const float* Wv = (const float*)d_in[3];
  float* out = (float*)d_out;
  char* ws = (char*)d_ws;
  ushort* Wt = (ushort*)ws;                                        // 768 KB
  ushort* qb = (ushort*)(ws + 786432);                             // 4 MB each
  ushort* kb = qb + (size_t)M_ * H_;
  ushort* vT = kb + (size_t)M_ * H_;
  float* Opart = (float*)(ws + 786432 + 3 * (size_t)M_ * H_ * 2);  // 36 MB
  float* ml = Opart + (size_t)1152 * 64 * 128;                     // 0.6 MB
  ushort* xbuf = (ushort*)Opart;   // alias: xb dead before flash writes Opart

  hipLaunchKernelGGL(wt_kernel,   dim3(384), dim3(256), 0, stream, Wq, Wk, Wv, Wt);
  hipLaunchKernelGGL(xb_kernel,   dim3(8192), dim3(256), 0, stream, x, xbuf);
  hipLaunchKernelGGL(qkv_gemm,    dim3(128, 3), dim3(256), 0, stream, xbuf, Wt, qb, kb, vT);
  hipLaunchKernelGGL(flash_kernel,dim3(8, 64, 4), dim3(256), 0, stream, qb, kb, vT, Opart, ml);
  hipLaunchKernelGGL(combine_kernel, dim3(64, 4), dim3(256), 0, stream, Opart, ml, out);
}

// Round 5
// 272.534 us; speedup vs baseline: 1.0235x; 1.0235x over previous
//
#include <hip/hip_runtime.h>

#define B_ 4
#define S_ 4096
#define E_ 1024
#define H_ 128
#define M_ (B_*S_)   // 16384

typedef __attribute__((ext_vector_type(8))) short bf16x8;
typedef __attribute__((ext_vector_type(4))) float f32x4;
typedef __attribute__((ext_vector_type(2))) unsigned int uint2v;

__device__ inline ushort f2bf(float f) {
  union { float f; unsigned u; } v; v.f = f;
  unsigned r = v.u + 0x7fffu + ((v.u >> 16) & 1u);   // RNE
  return (ushort)(r >> 16);
}

// ---- gfx950 cross-lane primitives (register-file, ~2cyc vs ~120cyc ds_bpermute) ----
__device__ inline void pl16sw(unsigned &x, unsigned &y) {
#if __has_builtin(__builtin_amdgcn_permlane16_swap)
  uint2v r = __builtin_amdgcn_permlane16_swap(x, y, false, false);
  x = r.x; y = r.y;
#else
  asm("v_permlane16_swap_b32 %0, %1" : "+v"(x), "+v"(y));
#endif
}
__device__ inline void pl32sw(unsigned &x, unsigned &y) {
#if __has_builtin(__builtin_amdgcn_permlane32_swap)
  uint2v r = __builtin_amdgcn_permlane32_swap(x, y, false, false);
  x = r.x; y = r.y;
#else
  asm("v_permlane32_swap_b32 %0, %1" : "+v"(x), "+v"(y));
#endif
}
// reduce over the 4 quads (lanes {col, col+16, col+32, col+48}); result broadcast to all
__device__ inline float red4max(float v) {
  union { float f; unsigned u; } a, b;
  a.f = v; b.f = v; pl16sw(a.u, b.u);
  float m1 = fmaxf(a.f, b.f);
  a.f = m1; b.f = m1; pl32sw(a.u, b.u);
  return fmaxf(a.f, b.f);
}
__device__ inline float red4sum(float v) {
  union { float f; unsigned u; } a, b;
  a.f = v; b.f = v; pl16sw(a.u, b.u);
  float s1 = a.f + b.f;
  a.f = s1; b.f = s1; pl32sw(a.u, b.u);
  return a.f + b.f;
}
__device__ inline unsigned cvt_pk_bf16(float lo, float hi) {
  unsigned w;
  asm("v_cvt_pk_bf16_f32 %0, %1, %2" : "=v"(w) : "v"(lo), "v"(hi));
  return w;
}

#define GLLDS16(g, l) __builtin_amdgcn_global_load_lds( \
    (const __attribute__((address_space(1))) void*)(g), \
    (__attribute__((address_space(3))) void*)(l), 16, 0, 0)

// ---------- kernel 1: W [1024][128] f32 (x3) -> Wt [3][128][1024] bf16 ----------
__global__ __launch_bounds__(256) void wt_kernel(const float* __restrict__ Wq,
    const float* __restrict__ Wk, const float* __restrict__ Wv,
    ushort* __restrict__ Wt) {
  int bid = blockIdx.x;               // 384 = 3 mats * 4 h-tiles * 32 e-tiles
  int mat = bid >> 7;
  int rem = bid & 127;
  int ht = rem >> 5, et = rem & 31;
  const float* W = mat == 0 ? Wq : (mat == 1 ? Wk : Wv);
  int e0 = et * 32, h0 = ht * 32;
  __shared__ float tl[32][33];
  int t = threadIdx.x;
  int r = t >> 3, c = (t & 7) << 2;
  const float4 f = *(const float4*)(W + (size_t)(e0 + r) * H_ + h0 + c);
  tl[r][c] = f.x; tl[r][c+1] = f.y; tl[r][c+2] = f.z; tl[r][c+3] = f.w;
  __syncthreads();
  ushort4 o;
  o.x = f2bf(tl[c+0][r]); o.y = f2bf(tl[c+1][r]);
  o.z = f2bf(tl[c+2][r]); o.w = f2bf(tl[c+3][r]);
  *(ushort4*)(Wt + ((size_t)mat*H_ + h0 + r) * E_ + e0 + c) = o;
}

// ---------- kernel 2: x f32 -> bf16 (memory-bound) ----------
__global__ __launch_bounds__(256) void xb_kernel(const float* __restrict__ x,
                                                 ushort* __restrict__ xb) {
  size_t i = ((size_t)blockIdx.x * 256 + threadIdx.x) * 8;
  float4 f0 = *(const float4*)(x + i);
  float4 f1 = *(const float4*)(x + i + 4);
  alignas(16) ushort us[8];
  us[0]=f2bf(f0.x); us[1]=f2bf(f0.y); us[2]=f2bf(f0.z); us[3]=f2bf(f0.w);
  us[4]=f2bf(f1.x); us[5]=f2bf(f1.y); us[6]=f2bf(f1.z); us[7]=f2bf(f1.w);
  *(uint4*)(xb + i) = *(uint4*)&us[0];
}

// ---------- kernel 3: QKV GEMM, m97-style: 128x128 tile, BK=64, global_load_lds ----------
__global__ __launch_bounds__(256, 2) void qkv_gemm(const ushort* __restrict__ xb,
    const ushort* __restrict__ Wt, ushort* __restrict__ qo,
    ushort* __restrict__ ko, ushort* __restrict__ vTo) {
  const int m0 = blockIdx.x * 128;
  const int mat = blockIdx.y;
  const ushort* Bsrc = Wt + (size_t)mat * H_ * E_;
  __shared__ ushort As[2][128 * 64];
  __shared__ ushort Bs[2][128 * 64];
  const int tid = threadIdx.x;
  const int wave = tid >> 6, lane = tid & 63;
  const int col = lane & 15, quad = lane >> 4;
  const int wr = wave >> 1, wc = wave & 1;

  f32x4 acc[4][4];
  #pragma unroll
  for (int i = 0; i < 4; i++)
    #pragma unroll
    for (int j = 0; j < 4; j++) acc[i][j] = (f32x4){0.f,0.f,0.f,0.f};

  const int srow = lane >> 3;
  const int sunit = (lane & 7) ^ srow;
  const int gcol = sunit * 8;

  #define STAGE_QKV(it, bufi) do { \
    _Pragma("unroll") \
    for (int j = 0; j < 4; j++) { \
      int rbase = wave*8 + j*32; \
      GLLDS16(xb + (size_t)(m0 + rbase + srow) * E_ + (it)*64 + gcol, \
              &As[bufi][rbase * 64]); \
      GLLDS16(Bsrc + (size_t)(rbase + srow) * E_ + (it)*64 + gcol, \
              &Bs[bufi][rbase * 64]); \
    } \
  } while (0)

  STAGE_QKV(0, 0);
  __syncthreads();

  for (int it = 0; it < 16; it++) {
    if (it < 15) STAGE_QKV(it + 1, (it + 1) & 1);
    const ushort* a = &As[it & 1][0];
    const ushort* bb = &Bs[it & 1][0];
    #pragma unroll
    for (int kc = 0; kc < 2; kc++) {
      bf16x8 af[4], bf[4];
      #pragma unroll
      for (int mi = 0; mi < 4; mi++) {
        int rr = wr*64 + mi*16 + col;
        af[mi] = *(const bf16x8*)(a + rr*64 + (((kc*4 + quad) ^ (col & 7)) * 8));
      }
      #pragma unroll
      for (int ni = 0; ni < 4; ni++) {
        int rr = wc*64 + ni*16 + col;
        bf[ni] = *(const bf16x8*)(bb + rr*64 + (((kc*4 + quad) ^ (col & 7)) * 8));
      }
      #pragma unroll
      for (int mi = 0; mi < 4; mi++)
        #pragma unroll
        for (int ni = 0; ni < 4; ni++)
          acc[mi][ni] = __builtin_amdgcn_mfma_f32_16x16x32_bf16(af[mi], bf[ni], acc[mi][ni], 0, 0, 0);
    }
    __syncthreads();
  }

  if (mat == 2) {
    int bb = m0 >> 12;
    int sbase = (m0 & 4095) + wr * 64;
    #pragma unroll
    for (int ni = 0; ni < 4; ni++) {
      int n = wc*64 + ni*16 + col;
      #pragma unroll
      for (int mi = 0; mi < 4; mi++) {
        int s = sbase + mi*16 + quad*4;
        ushort4 o;
        o.x = f2bf(acc[mi][ni][0]); o.y = f2bf(acc[mi][ni][1]);
        o.z = f2bf(acc[mi][ni][2]); o.w = f2bf(acc[mi][ni][3]);
        *(ushort4*)(vTo + ((size_t)(bb * H_ + n)) * S_ + s) = o;
      }
    }
  } else {
    ushort* dst = (mat == 0 ? qo : ko);
    #pragma unroll
    for (int ni = 0; ni < 4; ni++) {
      int n = wc*64 + ni*16 + col;
      #pragma unroll
      for (int mi = 0; mi < 4; mi++) {
        int row = m0 + wr*64 + mi*16 + quad*4;
        #pragma unroll
        for (int r = 0; r < 4; r++)
          dst[(size_t)(row + r) * H_ + n] = f2bf(acc[mi][ni][r]);
      }
    }
  }
}

// ---------- kernel 4: causal flash, split-K, ONE 64-row tile per WG, KVBLK=32 ----------
// grid (c=8, t=64 reversed, b=4): 1152 active blocks (2x R2's pair concurrency).
// Body is EXACTLY R2's proven kernel (reg-staged K, 16KB LDS, permlane softmax,
// in-reg P, T13/T14) with tile B stripped. Register-allocator A/B across rounds:
//   R2  pair  (256,2) 16KB  -> 112 VGPR, fast (84.8us)
//   R1  single(256,4) 16KB  ->  64 VGPR, spill (144.6us)   <- bound caused squeeze
//   R3/4 single(256,2) 32KB+gload_lds -> 76 VGPR, spill (150us)
// This round: single (256,2) 16KB reg-staged -> expect ~100-112 VGPR, no spill.
#define CHUNK_ 512
__global__ __launch_bounds__(256, 2) void flash_kernel(const ushort* __restrict__ q,
    const ushort* __restrict__ k, const ushort* __restrict__ vT,
    float* __restrict__ Opart, float* __restrict__ ml) {
  const float SL2E = 0.08838834764831845f * 1.44269504088896340736f;
  int c = blockIdx.x;
  int t = 63 - (int)blockIdx.y;               // heavy tiles first
  int b = blockIdx.z;
  if (t < 8 * c) return;
  int a = t >> 3, rr = t & 7;
  int slot = b * 288 + (a + 1) * (4 * a + rr) + c;

  int wave = threadIdx.x >> 6, lane = threadIdx.x & 63;
  int col = lane & 15, quad = lane >> 4;
  int q0 = t * 64 + wave * 16;
  const ushort* qb = q + (size_t)b * S_ * H_;
  const ushort* kbp = k + (size_t)b * S_ * H_;
  const ushort* vb = vT + (size_t)b * H_ * S_;

  __shared__ ushort kl[2][32 * 128];          // K block double-buffer, 16 KB

  bf16x8 qf[4];
  {
    const ushort* qp = qb + (size_t)(q0 + col) * H_ + quad * 8;
    #pragma unroll
    for (int kc = 0; kc < 4; kc++) qf[kc] = *(const bf16x8*)(qp + kc * 32);
  }

  f32x4 O[8];
  #pragma unroll
  for (int d = 0; d < 8; d++) O[d] = (f32x4){0.f,0.f,0.f,0.f};
  float m = -1e30f, l = 0.f;

  const int c0 = c * CHUNK_;
  const int kend = min(c0 + CHUNK_, t * 64 + 64);
  const int nblk = (kend - c0 + 31) >> 5;
  const int qlim = q0 + 15;

  const int sk0 = wave * 8 + quad;            // staged K row (this thread), +4 for second
  const int gu0 = (col ^ (sk0 & 15)) * 8;     // pre-swizzled global src unit
  const int gu1 = (col ^ ((sk0 + 4) & 15)) * 8;
  ushort* ld0 = &kl[0][sk0 * 128 + col * 8];
  ushort* ld1 = &kl[0][(sk0 + 4) * 128 + col * 8];
  const size_t lbuf = 32 * 128;

  const ushort* vbase = vb + (size_t)col * S_ + c0 + quad * 8;

  { // prologue: stage block 0
    const ushort* kp = kbp + (size_t)(c0 + sk0) * H_;
    *(uint4*)ld0 = *(const uint4*)(kp + gu0);
    *(uint4*)ld1 = *(const uint4*)(kp + 4 * H_ + gu1);
  }
  __syncthreads();

  for (int ib = 0; ib < nblk; ib++) {
    const int kb0 = c0 + ib * 32;
    uint4 a0, a1;
    const bool pre = (ib + 1 < nblk);
    if (pre) {                                // T14: issue loads now, write LDS after compute
      const ushort* kp = kbp + (size_t)(kb0 + 32 + sk0) * H_;
      a0 = *(const uint4*)(kp + gu0);
      a1 = *(const uint4*)(kp + 4 * H_ + gu1);
    }
    if (kb0 <= qlim) {                        // wave-uniform
      // K fragments from LDS
      const ushort* kcur = &kl[ib & 1][0];
      bf16x8 kf0[4], kf1[4];
      #pragma unroll
      for (int kc = 0; kc < 4; kc++) {
        int u = quad + kc * 4;
        kf0[kc] = *(const bf16x8*)(kcur + col*128        + ((u ^ col) * 8));
        kf1[kc] = *(const bf16x8*)(kcur + (16 + col)*128 + ((u ^ col) * 8));
      }
      // QK^T: two independent chains
      f32x4 sv0 = (f32x4){0.f,0.f,0.f,0.f}, sv1 = (f32x4){0.f,0.f,0.f,0.f};
      __builtin_amdgcn_s_setprio(1);
      #pragma unroll
      for (int kc = 0; kc < 4; kc++) {
        sv0 = __builtin_amdgcn_mfma_f32_16x16x32_bf16(kf0[kc], qf[kc], sv0, 0, 0, 0);
        sv1 = __builtin_amdgcn_mfma_f32_16x16x32_bf16(kf1[kc], qf[kc], sv1, 0, 0, 0);
      }
      __builtin_amdgcn_s_setprio(0);
      // V fragments group 0 (d=0..3): issue before softmax
      bf16x8 vfA[4];
      #pragma unroll
      for (int j = 0; j < 4; j++)
        vfA[j] = *(const bf16x8*)(vbase + ib * 32 + (size_t)(j * 16) * S_);
      // softmax: s[r]=key kb0+quad*4+r, s[4+r]=key kb0+16+quad*4+r; row q0+col
      float s[8];
      #pragma unroll
      for (int r = 0; r < 4; r++) { s[r] = sv0[r]; s[4 + r] = sv1[r]; }
      if (kb0 + 31 > q0) {
        #pragma unroll
        for (int r = 0; r < 4; r++) {
          if (kb0 + quad * 4 + r      > q0 + col) s[r]     = -1e30f;
          if (kb0 + 16 + quad * 4 + r > q0 + col) s[4 + r] = -1e30f;
        }
      }
      float cm = s[0];
      #pragma unroll
      for (int j = 1; j < 8; j++) cm = fmaxf(cm, s[j]);
      cm = red4max(cm);
      if (!__all(cm <= m)) {                  // T13 exact skip (alpha==1 bit-identical)
        float mn = fmaxf(m, cm);
        float alpha = exp2f((m - mn) * SL2E);
        l *= alpha;
        #pragma unroll
        for (int d = 0; d < 8; d++) O[d] *= alpha;
        m = mn;
      }
      // V group 1 (d=4..7): issue mid-softmax
      bf16x8 vfB[4];
      #pragma unroll
      for (int j = 0; j < 4; j++)
        vfB[j] = *(const bf16x8*)(vbase + ib * 32 + (size_t)((4 + j) * 16) * S_);
      // p overwrites s in place (saves 8 regs vs separate p[])
      float rs = 0.f;
      #pragma unroll
      for (int j = 0; j < 8; j++) { s[j] = exp2f((s[j] - m) * SL2E); rs += s[j]; }
      l += red4sum(rs);
      // P -> bf16x8 B-fragment, in-register permlane network (all-static indexing)
      unsigned w0 = cvt_pk_bf16(s[0], s[1]);
      unsigned w1 = cvt_pk_bf16(s[2], s[3]);
      unsigned w2 = cvt_pk_bf16(s[4], s[5]);
      unsigned w3 = cvt_pk_bf16(s[6], s[7]);
      pl32sw(w0, w2); pl32sw(w1, w3);
      pl16sw(w0, w2); pl16sw(w1, w3);
      union { uint4 u4; bf16x8 v; } pu;
      pu.u4 = make_uint4(w0, w1, w2, w3);
      // PV
      __builtin_amdgcn_s_setprio(1);
      #pragma unroll
      for (int j = 0; j < 4; j++)
        O[j] = __builtin_amdgcn_mfma_f32_16x16x32_bf16(vfA[j], pu.v, O[j], 0, 0, 0);
      #pragma unroll
      for (int j = 0; j < 4; j++)
        O[4 + j] = __builtin_amdgcn_mfma_f32_16x16x32_bf16(vfB[j], pu.v, O[4 + j], 0, 0, 0);
      __builtin_amdgcn_s_setprio(0);
    }
    if (pre) {                                // LDS write late: vmcnt hidden under compute
      size_t off = ((ib + 1) & 1) * lbuf;
      *(uint4*)(ld0 + off) = a0;
      *(uint4*)(ld1 + off) = a1;
    }
    __syncthreads();
  }

  float* Op = Opart + (size_t)slot * (64 * 128) + (size_t)(wave * 16 + col) * 128 + quad * 4;
  #pragma unroll
  for (int d = 0; d < 8; d++) *(f32x4*)(Op + d * 16) = O[d];
  if (quad == 0)
    *(float2*)(ml + (size_t)slot * 128 + (size_t)(wave * 16 + col) * 2) = make_float2(m, l);
}

// ---------- kernel 5: combine split-K partials ----------
__global__ __launch_bounds__(256) void combine_kernel(const float* __restrict__ Opart,
    const float* __restrict__ ml, float* __restrict__ out) {
  const float SL2E = 0.08838834764831845f * 1.44269504088896340736f;
  int tile = blockIdx.x, b = blockIdx.y;
  int a = tile >> 3, rr = tile & 7;
  int nc = a + 1;
  int base = b * 288 + (a + 1) * (4 * a + rr);
  int tid = threadIdx.x;
  int row = tid >> 2;
  int cs = (tid & 3) * 4;
  float m_c[8], l_c[8];
  float mstar = -1e30f;
  for (int ci = 0; ci < nc; ci++) {
    m_c[ci] = ml[(size_t)(base + ci) * 128 + row * 2];
    l_c[ci] = ml[(size_t)(base + ci) * 128 + row * 2 + 1];
    mstar = fmaxf(mstar, m_c[ci]);
  }
  float denom = 0.f;
  float w_c[8];
  for (int ci = 0; ci < nc; ci++) {
    w_c[ci] = exp2f((m_c[ci] - mstar) * SL2E);
    denom += w_c[ci] * l_c[ci];
  }
  float inv = 1.f / denom;
  f32x4 acc[8];
  #pragma unroll
  for (int i = 0; i < 8; i++) acc[i] = (f32x4){0.f,0.f,0.f,0.f};
  for (int ci = 0; ci < nc; ci++) {
    const float* Op = Opart + (size_t)(base + ci) * (64 * 128) + row * 128;
    float w = w_c[ci];
    #pragma unroll
    for (int i = 0; i < 8; i++) {
      f32x4 v = *(const f32x4*)(Op + cs + i * 16);
      acc[i] += w * v;
    }
  }
  float* o = out + ((size_t)(b * S_) + tile * 64 + row) * H_;
  #pragma unroll
  for (int i = 0; i < 8; i++) {
    f32x4 v = acc[i] * inv;
    *(f32x4*)(o + cs + i * 16) = v;
  }
}

extern "C" void kernel_launch(void* const* d_in, const int* in_sizes, int n_in,
                              void* d_out, int out_size, void* d_ws, size_t ws_size,
                              hipStream_t stream) {
  (void)in_sizes; (void)n_in; (void)out_size; (void)ws_size;
  const float* x  = (const float*)d_in[0];
  const float* Wq = (const float*)d_in[1];
  const float* Wk = (const float*)d_in[2];
  const float* Wv = (const float*)d_in[3];
  float* out = (float*)d_out;
  char* ws = (char*)d_ws;
  ushort* Wt = (ushort*)ws;                                        // 768 KB
  ushort* qb = (ushort*)(ws + 786432);                             // 4 MB each
  ushort* kb = qb + (size_t)M_ * H_;
  ushort* vT = kb + (size_t)M_ * H_;
  float* Opart = (float*)(ws + 786432 + 3 * (size_t)M_ * H_ * 2);  // 36 MB
  float* ml = Opart + (size_t)1152 * 64 * 128;                     // 0.6 MB
  ushort* xbuf = (ushort*)Opart;   // alias: xb dead before flash writes Opart

  hipLaunchKernelGGL(wt_kernel,   dim3(384), dim3(256), 0, stream, Wq, Wk, Wv, Wt);
  hipLaunchKernelGGL(xb_kernel,   dim3(8192), dim3(256), 0, stream, x, xbuf);
  hipLaunchKernelGGL(qkv_gemm,    dim3(128, 3), dim3(256), 0, stream, xbuf, Wt, qb, kb, vT);
  hipLaunchKernelGGL(flash_kernel,dim3(8, 64, 4), dim3(256), 0, stream, qb, kb, vT, Opart, ml);
  hipLaunchKernelGGL(combine_kernel, dim3(64, 4), dim3(256), 0, stream, Opart, ml, out);
}